// Round 2
// baseline (2158.564 us; speedup 1.0000x reference)
//
#include <hip/hip_runtime.h>
#include <hip/hip_bf16.h>

#define N_NODES 25000
#define N_EDGES 400000
#define H 128
#define NB 8          // nodes per block in node kernels

__global__ void init_s_kernel(const int* __restrict__ species,
                              const float* __restrict__ emb,
                              float* __restrict__ s) {
    int idx = blockIdx.x * blockDim.x + threadIdx.x;
    if (idx < N_NODES * H) {
        int n = idx >> 7;
        int h = idx & 127;
        s[idx] = emb[species[n] * H + h];
    }
}

// x = silu(s @ W1[i] + b1[i]) @ W2[i] + b2[i]   (per node: 128 -> 128 -> 384)
__global__ __launch_bounds__(128) void node_mlp_kernel(
    const float* __restrict__ s,
    const float* __restrict__ W1, const float* __restrict__ b1,
    const float* __restrict__ W2, const float* __restrict__ b2,
    float* __restrict__ x, int layer)
{
    __shared__ float s_sh[NB][H];
    __shared__ float hid_sh[NB][H];
    const int t = threadIdx.x;
    const int n0 = blockIdx.x * NB;

    #pragma unroll
    for (int nb = 0; nb < NB; nb++) {
        int n = n0 + nb;
        s_sh[nb][t] = (n < N_NODES) ? s[(size_t)n * H + t] : 0.f;
    }
    __syncthreads();

    const float* W1p = W1 + (size_t)layer * H * H;
    float b1v = b1[layer * H + t];
    float acc[NB];
    #pragma unroll
    for (int nb = 0; nb < NB; nb++) acc[nb] = b1v;
    for (int h = 0; h < H; h++) {
        float w = W1p[h * H + t];
        #pragma unroll
        for (int nb = 0; nb < NB; nb++) acc[nb] += s_sh[nb][h] * w;
    }
    #pragma unroll
    for (int nb = 0; nb < NB; nb++) {
        float z = acc[nb];
        hid_sh[nb][t] = z / (1.f + expf(-z));   // silu
    }
    __syncthreads();

    const float* W2p = W2 + (size_t)layer * H * 384;
    float c0 = b2[layer * 384 + t];
    float c1 = b2[layer * 384 + 128 + t];
    float c2 = b2[layer * 384 + 256 + t];
    float a0[NB], a1[NB], a2[NB];
    #pragma unroll
    for (int nb = 0; nb < NB; nb++) { a0[nb] = c0; a1[nb] = c1; a2[nb] = c2; }
    for (int h = 0; h < H; h++) {
        float w0 = W2p[h * 384 + t];
        float w1 = W2p[h * 384 + 128 + t];
        float w2 = W2p[h * 384 + 256 + t];
        #pragma unroll
        for (int nb = 0; nb < NB; nb++) {
            float hv = hid_sh[nb][h];
            a0[nb] += hv * w0; a1[nb] += hv * w1; a2[nb] += hv * w2;
        }
    }
    #pragma unroll
    for (int nb = 0; nb < NB; nb++) {
        int n = n0 + nb;
        if (n < N_NODES) {
            x[(size_t)n * 384 + t]       = a0[nb];
            x[(size_t)n * 384 + 128 + t] = a1[nb];
            x[(size_t)n * 384 + 256 + t] = a2[nb];
        }
    }
}

// Per edge: rbf -> Wij (on the fly) -> phi = Wij * x[recv] -> ds/dv atomics to sender
__global__ __launch_bounds__(256) void edge_kernel(
    const int* __restrict__ senders, const int* __restrict__ receivers,
    const float* __restrict__ dir_ij, const float* __restrict__ dists,
    const float* __restrict__ Wf, const float* __restrict__ bf,
    const float* __restrict__ x, const float* __restrict__ v,
    float* __restrict__ ds_acc, float* __restrict__ dv_acc, int layer)
{
    const int sub = threadIdx.x >> 7;   // 2 sub-groups of 128 threads
    const int t = threadIdx.x & 127;
    __shared__ float rbf_sh[2][20];

    const int e = blockIdx.x * 2 + sub;
    const bool active = (e < N_EDGES);

    int snd = 0, rcv = 0;
    float d = 1.f;
    if (active) {
        snd = senders[e];
        rcv = receivers[e];
        d = dists[e];
    }
    const float PI = 3.14159265358979323846f;
    if (active && t < 20) {
        float npi = (float)(t + 1) * PI;
        rbf_sh[sub][t] = 1.41421356237309515f * sinf(npi * d) / d;
    }
    __syncthreads();

    if (active) {
        float u = d;
        float u2 = u * u, u4 = u2 * u2, u6 = u4 * u2, u7 = u6 * u, u8 = u4 * u4;
        float env = (u < 1.f) ? (1.f - 28.f * u6 + 48.f * u7 - 21.f * u8) : 0.f;

        float acc0 = bf[layer * 384 + t];
        float acc1 = bf[layer * 384 + 128 + t];
        float acc2 = bf[layer * 384 + 256 + t];
        const float* Wfp = Wf + layer * 384;
        #pragma unroll
        for (int n = 0; n < 20; n++) {
            float r = rbf_sh[sub][n];
            acc0 += r * Wfp[n * 768 + t];
            acc1 += r * Wfp[n * 768 + 128 + t];
            acc2 += r * Wfp[n * 768 + 256 + t];
        }
        const float* xr = x + (size_t)rcv * 384;
        float phi0 = acc0 * env * xr[t];
        float phi1 = acc1 * env * xr[128 + t];
        float phi2 = acc2 * env * xr[256 + t];

        const float* vr = v + (size_t)rcv * 384;
        float d0 = dir_ij[e * 3 + 0];
        float d1 = dir_ij[e * 3 + 1];
        float d2 = dir_ij[e * 3 + 2];

        atomicAdd(&ds_acc[(size_t)snd * H + t], phi0);
        atomicAdd(&dv_acc[(size_t)snd * 384 + t],       phi1 * d0 + phi2 * vr[t]);
        atomicAdd(&dv_acc[(size_t)snd * 384 + 128 + t], phi1 * d1 + phi2 * vr[128 + t]);
        atomicAdd(&dv_acc[(size_t)snd * 384 + 256 + t], phi1 * d2 + phi2 * vr[256 + t]);
    }
}

// Apply segment sums, then gated vector/scalar mixing block
__global__ __launch_bounds__(128) void node_update_kernel(
    float* __restrict__ s, float* __restrict__ v,
    const float* __restrict__ ds_acc, const float* __restrict__ dv_acc,
    const float* __restrict__ Wvm,
    const float* __restrict__ Wm1, const float* __restrict__ bm1,
    const float* __restrict__ Wm2, const float* __restrict__ bm2,
    const float* __restrict__ eps_raw_p, int layer)
{
    __shared__ float v_sh[NB][3][H];
    __shared__ float ts_sh[NB][2 * H];
    __shared__ float hid_sh[NB][H];
    const int t = threadIdx.x;
    const int n0 = blockIdx.x * NB;
    float er = eps_raw_p[0];
    float eps = rsqrtf(1.f + er * er);

    float s_new[NB];
    #pragma unroll
    for (int nb = 0; nb < NB; nb++) {
        int n = n0 + nb;
        if (n < N_NODES) {
            float sv = (s[(size_t)n * H + t] + ds_acc[(size_t)n * H + t]) * eps;
            s_new[nb] = sv;
            #pragma unroll
            for (int k = 0; k < 3; k++) {
                float vv = (v[(size_t)n * 384 + k * H + t] +
                            dv_acc[(size_t)n * 384 + k * H + t]) * eps;
                v_sh[nb][k][t] = vv;
            }
        } else {
            s_new[nb] = 0.f;
            #pragma unroll
            for (int k = 0; k < 3; k++) v_sh[nb][k][t] = 0.f;
        }
    }
    __syncthreads();

    // vw = v @ Wvm[i]; thread t holds columns t (v_l) and 128+t (v_r)
    const float* Wvp = Wvm + (size_t)layer * H * 256;
    float vl[NB][3], vr[NB][3];
    #pragma unroll
    for (int nb = 0; nb < NB; nb++)
        #pragma unroll
        for (int k = 0; k < 3; k++) { vl[nb][k] = 0.f; vr[nb][k] = 0.f; }
    for (int h = 0; h < H; h++) {
        float wl = Wvp[h * 256 + t];
        float wr = Wvp[h * 256 + 128 + t];
        #pragma unroll
        for (int nb = 0; nb < NB; nb++) {
            #pragma unroll
            for (int k = 0; k < 3; k++) {
                float vv = v_sh[nb][k][h];
                vl[nb][k] += vv * wl;
                vr[nb][k] += vv * wr;
            }
        }
    }

    #pragma unroll
    for (int nb = 0; nb < NB; nb++) {
        float vn = sqrtf(vr[nb][0] * vr[nb][0] + vr[nb][1] * vr[nb][1] +
                         vr[nb][2] * vr[nb][2] + 1e-8f);
        ts_sh[nb][t] = s_new[nb];
        ts_sh[nb][128 + t] = vn;
    }
    __syncthreads();

    const float* Wm1p = Wm1 + (size_t)layer * 256 * H;
    float hb = bm1[layer * H + t];
    float hacc[NB];
    #pragma unroll
    for (int nb = 0; nb < NB; nb++) hacc[nb] = hb;
    for (int h = 0; h < 256; h++) {
        float w = Wm1p[h * H + t];
        #pragma unroll
        for (int nb = 0; nb < NB; nb++) hacc[nb] += ts_sh[nb][h] * w;
    }
    #pragma unroll
    for (int nb = 0; nb < NB; nb++) {
        float z = hacc[nb];
        hid_sh[nb][t] = z / (1.f + expf(-z));
    }
    __syncthreads();

    const float* Wm2p = Wm2 + (size_t)layer * H * 384;
    float c0 = bm2[layer * 384 + t];
    float c1 = bm2[layer * 384 + 128 + t];
    float c2 = bm2[layer * 384 + 256 + t];
    float m0[NB], m1[NB], m2[NB];
    #pragma unroll
    for (int nb = 0; nb < NB; nb++) { m0[nb] = c0; m1[nb] = c1; m2[nb] = c2; }
    for (int h = 0; h < H; h++) {
        float w0 = Wm2p[h * 384 + t];
        float w1 = Wm2p[h * 384 + 128 + t];
        float w2 = Wm2p[h * 384 + 256 + t];
        #pragma unroll
        for (int nb = 0; nb < NB; nb++) {
            float hv = hid_sh[nb][h];
            m0[nb] += hv * w0; m1[nb] += hv * w1; m2[nb] += hv * w2;
        }
    }

    #pragma unroll
    for (int nb = 0; nb < NB; nb++) {
        int n = n0 + nb;
        if (n >= N_NODES) continue;
        float sum_lr = vr[nb][0] * vl[nb][0] + vr[nb][1] * vl[nb][1] +
                       vr[nb][2] * vl[nb][2];
        float s_out = (s_new[nb] + m0[nb] + m2[nb] * sum_lr) * eps;
        s[(size_t)n * H + t] = s_out;
        #pragma unroll
        for (int k = 0; k < 3; k++) {
            v[(size_t)n * 384 + k * H + t] =
                (v_sh[nb][k][t] + vl[nb][k] * m1[nb]) * eps;
        }
    }
}

extern "C" void kernel_launch(void* const* d_in, const int* in_sizes, int n_in,
                              void* d_out, int out_size, void* d_ws, size_t ws_size,
                              hipStream_t stream) {
    const int*   species   = (const int*)d_in[0];
    const int*   senders   = (const int*)d_in[1];
    const int*   receivers = (const int*)d_in[2];
    const float* dir_ij    = (const float*)d_in[3];
    const float* dists     = (const float*)d_in[4];
    const float* emb       = (const float*)d_in[5];
    const float* Wf        = (const float*)d_in[6];
    const float* bf        = (const float*)d_in[7];
    const float* W1        = (const float*)d_in[8];
    const float* b1        = (const float*)d_in[9];
    const float* W2        = (const float*)d_in[10];
    const float* b2        = (const float*)d_in[11];
    const float* Wvm       = (const float*)d_in[12];
    const float* Wm1       = (const float*)d_in[13];
    const float* bm1       = (const float*)d_in[14];
    const float* Wm2       = (const float*)d_in[15];
    const float* bm2       = (const float*)d_in[16];
    const float* eps_raw   = (const float*)d_in[17];

    float* s = (float*)d_out;                            // N*H
    float* v = (float*)d_out + (size_t)N_NODES * H;      // N*3*H

    float* x      = (float*)d_ws;                        // N*384
    float* ds_acc = x + (size_t)N_NODES * 384;           // N*128
    float* dv_acc = ds_acc + (size_t)N_NODES * H;        // N*384 (contiguous after ds_acc)

    // init: v = 0, s = emb[species]
    hipMemsetAsync(v, 0, (size_t)N_NODES * 384 * sizeof(float), stream);
    init_s_kernel<<<(N_NODES * H + 255) / 256, 256, 0, stream>>>(species, emb, s);

    for (int layer = 0; layer < 2; layer++) {
        // zero ds_acc + dv_acc in one contiguous memset (N * 512 floats)
        hipMemsetAsync(ds_acc, 0, (size_t)N_NODES * 512 * sizeof(float), stream);
        node_mlp_kernel<<<(N_NODES + NB - 1) / NB, 128, 0, stream>>>(
            s, W1, b1, W2, b2, x, layer);
        edge_kernel<<<(N_EDGES + 1) / 2, 256, 0, stream>>>(
            senders, receivers, dir_ij, dists, Wf, bf, x, v, ds_acc, dv_acc, layer);
        node_update_kernel<<<(N_NODES + NB - 1) / NB, 128, 0, stream>>>(
            s, v, ds_acc, dv_acc, Wvm, Wm1, bm1, Wm2, bm2, eps_raw, layer);
    }
}

// Round 6
// 1305.363 us; speedup vs baseline: 1.6536x; 1.6536x over previous
//
#include <hip/hip_runtime.h>
#include <hip/hip_bf16.h>

#define N_NODES 25000
#define N_EDGES 400000
#define H 128
#define NB 8          // nodes per block in node kernels

__global__ void init_s_kernel(const int* __restrict__ species,
                              const float* __restrict__ emb,
                              float* __restrict__ s) {
    int idx = blockIdx.x * blockDim.x + threadIdx.x;
    if (idx < N_NODES * H) {
        int n = idx >> 7;
        int h = idx & 127;
        s[idx] = emb[species[n] * H + h];
    }
}

// ---------- CSR build over senders ----------
__global__ void count_kernel(const int* __restrict__ senders, int* __restrict__ cnt) {
    int e = blockIdx.x * blockDim.x + threadIdx.x;
    if (e < N_EDGES) atomicAdd(&cnt[senders[e]], 1);
}

__global__ __launch_bounds__(1024) void scan_kernel(int* __restrict__ cnt,
                                                    int* __restrict__ offsets) {
    __shared__ int sh[1024];
    const int t = threadIdx.x;
    const int CH = 25;                    // 1024*25 >= 25000
    int base = t * CH;
    int lc[CH];
    int lsum = 0;
    #pragma unroll
    for (int i = 0; i < CH; i++) {
        int idx = base + i;
        int c = (idx < N_NODES) ? cnt[idx] : 0;
        lc[i] = c; lsum += c;
    }
    sh[t] = lsum;
    __syncthreads();
    for (int ofs = 1; ofs < 1024; ofs <<= 1) {
        int v = (t >= ofs) ? sh[t - ofs] : 0;
        __syncthreads();
        sh[t] += v;
        __syncthreads();
    }
    int run = (t > 0) ? sh[t - 1] : 0;
    #pragma unroll
    for (int i = 0; i < CH; i++) {
        int idx = base + i;
        if (idx < N_NODES) {
            offsets[idx] = run;
            cnt[idx] = run;               // cnt becomes the fill cursor
            run += lc[i];
        }
    }
    if (t == 1023) offsets[N_NODES] = sh[1023];
}

__global__ void fill_kernel(const int* __restrict__ senders,
                            int* __restrict__ cursor, int* __restrict__ edge_ids) {
    int e = blockIdx.x * blockDim.x + threadIdx.x;
    if (e < N_EDGES) {
        int pos = atomicAdd(&cursor[senders[e]], 1);
        edge_ids[pos] = e;
    }
}

// x = silu(s @ W1[i] + b1[i]) @ W2[i] + b2[i]   (per node: 128 -> 128 -> 384)
__global__ __launch_bounds__(128) void node_mlp_kernel(
    const float* __restrict__ s,
    const float* __restrict__ W1, const float* __restrict__ b1,
    const float* __restrict__ W2, const float* __restrict__ b2,
    float* __restrict__ x, int layer)
{
    __shared__ float s_sh[NB][H];
    __shared__ float hid_sh[NB][H];
    const int t = threadIdx.x;
    const int n0 = blockIdx.x * NB;

    #pragma unroll
    for (int nb = 0; nb < NB; nb++) {
        int n = n0 + nb;
        s_sh[nb][t] = (n < N_NODES) ? s[(size_t)n * H + t] : 0.f;
    }
    __syncthreads();

    const float* W1p = W1 + (size_t)layer * H * H;
    float b1v = b1[layer * H + t];
    float acc[NB];
    #pragma unroll
    for (int nb = 0; nb < NB; nb++) acc[nb] = b1v;
    for (int h = 0; h < H; h++) {
        float w = W1p[h * H + t];
        #pragma unroll
        for (int nb = 0; nb < NB; nb++) acc[nb] += s_sh[nb][h] * w;
    }
    #pragma unroll
    for (int nb = 0; nb < NB; nb++) {
        float z = acc[nb];
        hid_sh[nb][t] = z / (1.f + expf(-z));   // silu
    }
    __syncthreads();

    const float* W2p = W2 + (size_t)layer * H * 384;
    float c0 = b2[layer * 384 + t];
    float c1 = b2[layer * 384 + 128 + t];
    float c2 = b2[layer * 384 + 256 + t];
    float a0[NB], a1[NB], a2[NB];
    #pragma unroll
    for (int nb = 0; nb < NB; nb++) { a0[nb] = c0; a1[nb] = c1; a2[nb] = c2; }
    for (int h = 0; h < H; h++) {
        float w0 = W2p[h * 384 + t];
        float w1 = W2p[h * 384 + 128 + t];
        float w2 = W2p[h * 384 + 256 + t];
        #pragma unroll
        for (int nb = 0; nb < NB; nb++) {
            float hv = hid_sh[nb][h];
            a0[nb] += hv * w0; a1[nb] += hv * w1; a2[nb] += hv * w2;
        }
    }
    #pragma unroll
    for (int nb = 0; nb < NB; nb++) {
        int n = n0 + nb;
        if (n < N_NODES) {
            x[(size_t)n * 384 + t]       = a0[nb];
            x[(size_t)n * 384 + 128 + t] = a1[nb];
            x[(size_t)n * 384 + 256 + t] = a2[nb];
        }
    }
}

// Gather-based edge aggregation: one block (128 threads) per sender node.
// ds/dv accumulated in registers over the node's edge list, single store.
__global__ __launch_bounds__(128) void aggregate_kernel(
    const int* __restrict__ receivers,
    const int* __restrict__ offsets, const int* __restrict__ edge_ids,
    const float* __restrict__ dir_ij, const float* __restrict__ dists,
    const float* __restrict__ Wf, const float* __restrict__ bfb,
    const float* __restrict__ x, const float* __restrict__ v,
    float* __restrict__ ds_acc, float* __restrict__ dv_acc, int layer)
{
    const int t = threadIdx.x;          // feature 0..127
    const int lane = t & 63;
    const int node = blockIdx.x;

    // Wf slice for this layer into registers (amortized over node's edges)
    const float* Wfp = Wf + layer * 384;       // row stride 768 (L*3*H)
    float wf0[20], wf1[20], wf2[20];
    #pragma unroll
    for (int n = 0; n < 20; n++) {
        wf0[n] = Wfp[n * 768 + t];
        wf1[n] = Wfp[n * 768 + 128 + t];
        wf2[n] = Wfp[n * 768 + 256 + t];
    }
    float bf0 = bfb[layer * 384 + t];
    float bf1 = bfb[layer * 384 + 128 + t];
    float bf2 = bfb[layer * 384 + 256 + t];

    float accs = 0.f, av0 = 0.f, av1 = 0.f, av2 = 0.f;
    const int beg = offsets[node], end = offsets[node + 1];
    const float PI = 3.14159265358979323846f;

    for (int j = beg; j < end; j++) {
        int eid = edge_ids[j];
        int rcv = receivers[eid];
        float d  = dists[eid];
        float d0 = dir_ij[eid * 3 + 0];
        float d1 = dir_ij[eid * 3 + 1];
        float d2 = dir_ij[eid * 3 + 2];

        float u = d;
        float u2 = u * u, u4 = u2 * u2, u6 = u4 * u2, u7 = u6 * u, u8 = u4 * u4;
        float env = (u < 1.f) ? (1.f - 28.f * u6 + 48.f * u7 - 21.f * u8) : 0.f;

        // rbf: lanes 0..19 of each wave compute, broadcast via readlane
        float rb = 0.f;
        if (lane < 20) rb = 1.4142135623730951f * sinf((float)(lane + 1) * PI * d) / d;

        float w0 = bf0, w1 = bf1, w2 = bf2;
        #pragma unroll
        for (int n = 0; n < 20; n++) {
            float rn = __shfl(rb, n, 64);
            w0 = fmaf(rn, wf0[n], w0);
            w1 = fmaf(rn, wf1[n], w1);
            w2 = fmaf(rn, wf2[n], w2);
        }
        const float* xr = x + (size_t)rcv * 384;
        const float* vr = v + (size_t)rcv * 384;
        float phi0 = w0 * env * xr[t];
        float phi1 = w1 * env * xr[128 + t];
        float phi2 = w2 * env * xr[256 + t];

        accs += phi0;
        av0 = fmaf(phi1, d0, fmaf(phi2, vr[t],       av0));
        av1 = fmaf(phi1, d1, fmaf(phi2, vr[128 + t], av1));
        av2 = fmaf(phi1, d2, fmaf(phi2, vr[256 + t], av2));
    }

    ds_acc[(size_t)node * H + t] = accs;
    dv_acc[(size_t)node * 384 + t]       = av0;
    dv_acc[(size_t)node * 384 + 128 + t] = av1;
    dv_acc[(size_t)node * 384 + 256 + t] = av2;
}

// Apply segment sums, then gated vector/scalar mixing block
__global__ __launch_bounds__(128) void node_update_kernel(
    float* __restrict__ s, float* __restrict__ v,
    const float* __restrict__ ds_acc, const float* __restrict__ dv_acc,
    const float* __restrict__ Wvm,
    const float* __restrict__ Wm1, const float* __restrict__ bm1,
    const float* __restrict__ Wm2, const float* __restrict__ bm2,
    const float* __restrict__ eps_raw_p, int layer)
{
    __shared__ float v_sh[NB][3][H];
    __shared__ float ts_sh[NB][2 * H];
    __shared__ float hid_sh[NB][H];
    const int t = threadIdx.x;
    const int n0 = blockIdx.x * NB;
    float er = eps_raw_p[0];
    float eps = rsqrtf(1.f + er * er);

    float s_new[NB];
    #pragma unroll
    for (int nb = 0; nb < NB; nb++) {
        int n = n0 + nb;
        if (n < N_NODES) {
            float sv = (s[(size_t)n * H + t] + ds_acc[(size_t)n * H + t]) * eps;
            s_new[nb] = sv;
            #pragma unroll
            for (int k = 0; k < 3; k++) {
                float vv = (v[(size_t)n * 384 + k * H + t] +
                            dv_acc[(size_t)n * 384 + k * H + t]) * eps;
                v_sh[nb][k][t] = vv;
            }
        } else {
            s_new[nb] = 0.f;
            #pragma unroll
            for (int k = 0; k < 3; k++) v_sh[nb][k][t] = 0.f;
        }
    }
    __syncthreads();

    // vw = v @ Wvm[i]; thread t holds columns t (v_l) and 128+t (v_r)
    const float* Wvp = Wvm + (size_t)layer * H * 256;
    float vl[NB][3], vr[NB][3];
    #pragma unroll
    for (int nb = 0; nb < NB; nb++)
        #pragma unroll
        for (int k = 0; k < 3; k++) { vl[nb][k] = 0.f; vr[nb][k] = 0.f; }
    for (int h = 0; h < H; h++) {
        float wl = Wvp[h * 256 + t];
        float wr = Wvp[h * 256 + 128 + t];
        #pragma unroll
        for (int nb = 0; nb < NB; nb++) {
            #pragma unroll
            for (int k = 0; k < 3; k++) {
                float vv = v_sh[nb][k][h];
                vl[nb][k] += vv * wl;
                vr[nb][k] += vv * wr;
            }
        }
    }

    #pragma unroll
    for (int nb = 0; nb < NB; nb++) {
        float vn = sqrtf(vr[nb][0] * vr[nb][0] + vr[nb][1] * vr[nb][1] +
                         vr[nb][2] * vr[nb][2] + 1e-8f);
        ts_sh[nb][t] = s_new[nb];
        ts_sh[nb][128 + t] = vn;
    }
    __syncthreads();

    const float* Wm1p = Wm1 + (size_t)layer * 256 * H;
    float hb = bm1[layer * H + t];
    float hacc[NB];
    #pragma unroll
    for (int nb = 0; nb < NB; nb++) hacc[nb] = hb;
    for (int h = 0; h < 256; h++) {
        float w = Wm1p[h * H + t];
        #pragma unroll
        for (int nb = 0; nb < NB; nb++) hacc[nb] += ts_sh[nb][h] * w;
    }
    #pragma unroll
    for (int nb = 0; nb < NB; nb++) {
        float z = hacc[nb];
        hid_sh[nb][t] = z / (1.f + expf(-z));
    }
    __syncthreads();

    const float* Wm2p = Wm2 + (size_t)layer * H * 384;
    float c0 = bm2[layer * 384 + t];
    float c1 = bm2[layer * 384 + 128 + t];
    float c2 = bm2[layer * 384 + 256 + t];
    float m0[NB], m1[NB], m2[NB];
    #pragma unroll
    for (int nb = 0; nb < NB; nb++) { m0[nb] = c0; m1[nb] = c1; m2[nb] = c2; }
    for (int h = 0; h < H; h++) {
        float w0 = Wm2p[h * 384 + t];
        float w1 = Wm2p[h * 384 + 128 + t];
        float w2 = Wm2p[h * 384 + 256 + t];
        #pragma unroll
        for (int nb = 0; nb < NB; nb++) {
            float hv = hid_sh[nb][h];
            m0[nb] += hv * w0; m1[nb] += hv * w1; m2[nb] += hv * w2;
        }
    }

    #pragma unroll
    for (int nb = 0; nb < NB; nb++) {
        int n = n0 + nb;
        if (n >= N_NODES) continue;
        float sum_lr = vr[nb][0] * vl[nb][0] + vr[nb][1] * vl[nb][1] +
                       vr[nb][2] * vl[nb][2];
        float s_out = (s_new[nb] + m0[nb] + m2[nb] * sum_lr) * eps;
        s[(size_t)n * H + t] = s_out;
        #pragma unroll
        for (int k = 0; k < 3; k++) {
            v[(size_t)n * 384 + k * H + t] =
                (v_sh[nb][k][t] + vl[nb][k] * m1[nb]) * eps;
        }
    }
}

extern "C" void kernel_launch(void* const* d_in, const int* in_sizes, int n_in,
                              void* d_out, int out_size, void* d_ws, size_t ws_size,
                              hipStream_t stream) {
    const int*   species   = (const int*)d_in[0];
    const int*   senders   = (const int*)d_in[1];
    const int*   receivers = (const int*)d_in[2];
    const float* dir_ij    = (const float*)d_in[3];
    const float* dists     = (const float*)d_in[4];
    const float* emb       = (const float*)d_in[5];
    const float* Wf        = (const float*)d_in[6];
    const float* bf        = (const float*)d_in[7];
    const float* W1        = (const float*)d_in[8];
    const float* b1        = (const float*)d_in[9];
    const float* W2        = (const float*)d_in[10];
    const float* b2        = (const float*)d_in[11];
    const float* Wvm       = (const float*)d_in[12];
    const float* Wm1       = (const float*)d_in[13];
    const float* bm1       = (const float*)d_in[14];
    const float* Wm2       = (const float*)d_in[15];
    const float* bm2       = (const float*)d_in[16];
    const float* eps_raw   = (const float*)d_in[17];

    float* s = (float*)d_out;                            // N*H
    float* v = (float*)d_out + (size_t)N_NODES * H;      // N*3*H

    float* x      = (float*)d_ws;                        // N*384
    float* ds_acc = x + (size_t)N_NODES * 384;           // N*128
    float* dv_acc = ds_acc + (size_t)N_NODES * H;        // N*384
    int*   cursor   = (int*)(dv_acc + (size_t)N_NODES * 384);  // N (counts, then cursor)
    int*   offsets  = cursor + N_NODES;                        // N+1 (+pad)
    int*   edge_ids = offsets + N_NODES + 8;                   // E

    // CSR build (layer-independent)
    hipMemsetAsync(cursor, 0, N_NODES * sizeof(int), stream);
    count_kernel<<<(N_EDGES + 255) / 256, 256, 0, stream>>>(senders, cursor);
    scan_kernel<<<1, 1024, 0, stream>>>(cursor, offsets);
    fill_kernel<<<(N_EDGES + 255) / 256, 256, 0, stream>>>(senders, cursor, edge_ids);

    // init: v = 0, s = emb[species]
    hipMemsetAsync(v, 0, (size_t)N_NODES * 384 * sizeof(float), stream);
    init_s_kernel<<<(N_NODES * H + 255) / 256, 256, 0, stream>>>(species, emb, s);

    for (int layer = 0; layer < 2; layer++) {
        node_mlp_kernel<<<(N_NODES + NB - 1) / NB, 128, 0, stream>>>(
            s, W1, b1, W2, b2, x, layer);
        aggregate_kernel<<<N_NODES, 128, 0, stream>>>(
            receivers, offsets, edge_ids, dir_ij, dists, Wf, bf, x, v,
            ds_acc, dv_acc, layer);
        node_update_kernel<<<(N_NODES + NB - 1) / NB, 128, 0, stream>>>(
            s, v, ds_acc, dv_acc, Wvm, Wm1, bm1, Wm2, bm2, eps_raw, layer);
    }
}

// Round 8
// 1267.833 us; speedup vs baseline: 1.7026x; 1.0296x over previous
//
#include <hip/hip_runtime.h>
#include <hip/hip_bf16.h>

#define N_NODES 25000
#define N_EDGES 400000
#define H 128
#define NB 8           // nodes per block in node_update
#define NBM 16         // nodes per block in node_mlp

__global__ void init_s_kernel(const int* __restrict__ species,
                              const float* __restrict__ emb,
                              float* __restrict__ s) {
    int idx = blockIdx.x * blockDim.x + threadIdx.x;
    if (idx < N_NODES * H) {
        int n = idx >> 7;
        int h = idx & 127;
        s[idx] = emb[species[n] * H + h];
    }
}

// ---------- CSR build over senders ----------
__global__ void count_kernel(const int* __restrict__ senders, int* __restrict__ cnt) {
    int e = blockIdx.x * blockDim.x + threadIdx.x;
    if (e < N_EDGES) atomicAdd(&cnt[senders[e]], 1);
}

__global__ __launch_bounds__(1024) void scan_kernel(int* __restrict__ cnt,
                                                    int* __restrict__ offsets) {
    __shared__ int sh[1024];
    const int t = threadIdx.x;
    const int CH = 25;                    // 1024*25 >= 25000
    int base = t * CH;
    int lc[CH];
    int lsum = 0;
    #pragma unroll
    for (int i = 0; i < CH; i++) {
        int idx = base + i;
        int c = (idx < N_NODES) ? cnt[idx] : 0;
        lc[i] = c; lsum += c;
    }
    sh[t] = lsum;
    __syncthreads();
    for (int ofs = 1; ofs < 1024; ofs <<= 1) {
        int v = (t >= ofs) ? sh[t - ofs] : 0;
        __syncthreads();
        sh[t] += v;
        __syncthreads();
    }
    int run = (t > 0) ? sh[t - 1] : 0;
    #pragma unroll
    for (int i = 0; i < CH; i++) {
        int idx = base + i;
        if (idx < N_NODES) {
            offsets[idx] = run;
            cnt[idx] = run;               // cnt becomes the fill cursor
            run += lc[i];
        }
    }
    if (t == 1023) offsets[N_NODES] = sh[1023];
}

__global__ void fill_kernel(const int* __restrict__ senders,
                            int* __restrict__ cursor, int* __restrict__ edge_ids) {
    int e = blockIdx.x * blockDim.x + threadIdx.x;
    if (e < N_EDGES) {
        int pos = atomicAdd(&cursor[senders[e]], 1);
        edge_ids[pos] = e;
    }
}

// rbf[e][n] = sqrt(2)*sin((n+1)*pi*d)/d   (env NOT folded in; applied in aggregate)
__global__ void rbfenv_kernel(const float* __restrict__ dists,
                              float* __restrict__ rbf) {
    int idx = blockIdx.x * blockDim.x + threadIdx.x;
    if (idx < N_EDGES * 20) {
        int e = idx / 20;
        int n = idx - e * 20;
        float d = dists[e];
        const float PI = 3.14159265358979323846f;
        rbf[idx] = 1.4142135623730951f * sinf((float)(n + 1) * PI * d) / d;
    }
}

// x = silu(s @ W1[i] + b1[i]) @ W2[i] + b2[i]   (per node: 128 -> 128 -> 384)
__global__ __launch_bounds__(128, 4) void node_mlp_kernel(
    const float* __restrict__ s,
    const float* __restrict__ W1, const float* __restrict__ b1,
    const float* __restrict__ W2, const float* __restrict__ b2,
    float* __restrict__ x, int layer)
{
    __shared__ float s_sh[NBM][H];
    __shared__ float hid_sh[NBM][H];
    const int t = threadIdx.x;
    const int n0 = blockIdx.x * NBM;

    #pragma unroll
    for (int nb = 0; nb < NBM; nb++) {
        int n = n0 + nb;
        s_sh[nb][t] = (n < N_NODES) ? s[(size_t)n * H + t] : 0.f;
    }
    __syncthreads();

    const float* W1p = W1 + (size_t)layer * H * H;
    float b1v = b1[layer * H + t];
    float acc[NBM];
    #pragma unroll
    for (int nb = 0; nb < NBM; nb++) acc[nb] = b1v;
    for (int h = 0; h < H; h++) {
        float w = W1p[h * H + t];
        #pragma unroll
        for (int nb = 0; nb < NBM; nb++) acc[nb] += s_sh[nb][h] * w;
    }
    #pragma unroll
    for (int nb = 0; nb < NBM; nb++) {
        float z = acc[nb];
        hid_sh[nb][t] = z / (1.f + expf(-z));   // silu
    }
    __syncthreads();

    const float* W2p = W2 + (size_t)layer * H * 384;
    float c0 = b2[layer * 384 + t];
    float c1 = b2[layer * 384 + 128 + t];
    float c2 = b2[layer * 384 + 256 + t];
    float a0[NBM], a1[NBM], a2[NBM];
    #pragma unroll
    for (int nb = 0; nb < NBM; nb++) { a0[nb] = c0; a1[nb] = c1; a2[nb] = c2; }
    for (int h = 0; h < H; h++) {
        float w0 = W2p[h * 384 + t];
        float w1 = W2p[h * 384 + 128 + t];
        float w2 = W2p[h * 384 + 256 + t];
        #pragma unroll
        for (int nb = 0; nb < NBM; nb++) {
            float hv = hid_sh[nb][h];
            a0[nb] += hv * w0; a1[nb] += hv * w1; a2[nb] += hv * w2;
        }
    }
    #pragma unroll
    for (int nb = 0; nb < NBM; nb++) {
        int n = n0 + nb;
        if (n < N_NODES) {
            x[(size_t)n * 384 + t]       = a0[nb];
            x[(size_t)n * 384 + 128 + t] = a1[nb];
            x[(size_t)n * 384 + 256 + t] = a2[nb];
        }
    }
}

// Gather-based edge aggregation: one block (128 threads) per sender node.
// rbf precomputed; Wf slice held in registers (launch_bounds allows 128 VGPR).
__global__ __launch_bounds__(128, 4) void aggregate_kernel(
    const int* __restrict__ receivers,
    const int* __restrict__ offsets, const int* __restrict__ edge_ids,
    const float* __restrict__ dir_ij, const float* __restrict__ dists,
    const float* __restrict__ rbf,
    const float* __restrict__ Wf, const float* __restrict__ bfb,
    const float* __restrict__ x, const float* __restrict__ v,
    float* __restrict__ ds_acc, float* __restrict__ dv_acc, int layer)
{
    const int t = threadIdx.x;          // feature 0..127
    const int node = blockIdx.x;

    // Wf slice for this layer into registers (amortized over node's edges)
    const float* Wfp = Wf + layer * 384;       // row stride 768 (L*3*H)
    float wf0[20], wf1[20], wf2[20];
    #pragma unroll
    for (int n = 0; n < 20; n++) {
        wf0[n] = Wfp[n * 768 + t];
        wf1[n] = Wfp[n * 768 + 128 + t];
        wf2[n] = Wfp[n * 768 + 256 + t];
    }
    float bf0 = bfb[layer * 384 + t];
    float bf1 = bfb[layer * 384 + 128 + t];
    float bf2 = bfb[layer * 384 + 256 + t];

    float accs = 0.f, av0 = 0.f, av1 = 0.f, av2 = 0.f;
    const int beg = offsets[node], end = offsets[node + 1];

    for (int j = beg; j < end; j++) {
        int eid = edge_ids[j];
        int rcv = receivers[eid];
        float d  = dists[eid];
        float d0 = dir_ij[eid * 3 + 0];
        float d1 = dir_ij[eid * 3 + 1];
        float d2 = dir_ij[eid * 3 + 2];

        float u = d;
        float u2 = u * u, u4 = u2 * u2, u6 = u4 * u2, u7 = u6 * u, u8 = u4 * u4;
        float env = (u < 1.f) ? (1.f - 28.f * u6 + 48.f * u7 - 21.f * u8) : 0.f;

        // 20 rbf values: uniform across block, 5 float4 broadcast loads
        const float4* rp = (const float4*)(rbf + (size_t)eid * 20);
        float4 q0 = rp[0], q1 = rp[1], q2 = rp[2], q3 = rp[3], q4 = rp[4];
        float r[20] = { q0.x, q0.y, q0.z, q0.w, q1.x, q1.y, q1.z, q1.w,
                        q2.x, q2.y, q2.z, q2.w, q3.x, q3.y, q3.z, q3.w,
                        q4.x, q4.y, q4.z, q4.w };

        float w0 = bf0, w1 = bf1, w2 = bf2;
        #pragma unroll
        for (int n = 0; n < 20; n++) {
            w0 = fmaf(r[n], wf0[n], w0);
            w1 = fmaf(r[n], wf1[n], w1);
            w2 = fmaf(r[n], wf2[n], w2);
        }
        const float* xr = x + (size_t)rcv * 384;
        const float* vr = v + (size_t)rcv * 384;
        float phi0 = w0 * env * xr[t];
        float phi1 = w1 * env * xr[128 + t];
        float phi2 = w2 * env * xr[256 + t];

        accs += phi0;
        av0 = fmaf(phi1, d0, fmaf(phi2, vr[t],       av0));
        av1 = fmaf(phi1, d1, fmaf(phi2, vr[128 + t], av1));
        av2 = fmaf(phi1, d2, fmaf(phi2, vr[256 + t], av2));
    }

    ds_acc[(size_t)node * H + t] = accs;
    dv_acc[(size_t)node * 384 + t]       = av0;
    dv_acc[(size_t)node * 384 + 128 + t] = av1;
    dv_acc[(size_t)node * 384 + 256 + t] = av2;
}

// Apply segment sums, then gated vector/scalar mixing block
__global__ __launch_bounds__(128) void node_update_kernel(
    float* __restrict__ s, float* __restrict__ v,
    const float* __restrict__ ds_acc, const float* __restrict__ dv_acc,
    const float* __restrict__ Wvm,
    const float* __restrict__ Wm1, const float* __restrict__ bm1,
    const float* __restrict__ Wm2, const float* __restrict__ bm2,
    const float* __restrict__ eps_raw_p, int layer)
{
    __shared__ float v_sh[NB][3][H];
    __shared__ float ts_sh[NB][2 * H];
    __shared__ float hid_sh[NB][H];
    const int t = threadIdx.x;
    const int n0 = blockIdx.x * NB;
    float er = eps_raw_p[0];
    float eps = rsqrtf(1.f + er * er);

    float s_new[NB];
    #pragma unroll
    for (int nb = 0; nb < NB; nb++) {
        int n = n0 + nb;
        if (n < N_NODES) {
            float sv = (s[(size_t)n * H + t] + ds_acc[(size_t)n * H + t]) * eps;
            s_new[nb] = sv;
            #pragma unroll
            for (int k = 0; k < 3; k++) {
                float vv = (v[(size_t)n * 384 + k * H + t] +
                            dv_acc[(size_t)n * 384 + k * H + t]) * eps;
                v_sh[nb][k][t] = vv;
            }
        } else {
            s_new[nb] = 0.f;
            #pragma unroll
            for (int k = 0; k < 3; k++) v_sh[nb][k][t] = 0.f;
        }
    }
    __syncthreads();

    // vw = v @ Wvm[i]; thread t holds columns t (v_l) and 128+t (v_r)
    const float* Wvp = Wvm + (size_t)layer * H * 256;
    float vl[NB][3], vr[NB][3];
    #pragma unroll
    for (int nb = 0; nb < NB; nb++)
        #pragma unroll
        for (int k = 0; k < 3; k++) { vl[nb][k] = 0.f; vr[nb][k] = 0.f; }
    for (int h = 0; h < H; h++) {
        float wl = Wvp[h * 256 + t];
        float wr = Wvp[h * 256 + 128 + t];
        #pragma unroll
        for (int nb = 0; nb < NB; nb++) {
            #pragma unroll
            for (int k = 0; k < 3; k++) {
                float vv = v_sh[nb][k][h];
                vl[nb][k] += vv * wl;
                vr[nb][k] += vv * wr;
            }
        }
    }

    #pragma unroll
    for (int nb = 0; nb < NB; nb++) {
        float vn = sqrtf(vr[nb][0] * vr[nb][0] + vr[nb][1] * vr[nb][1] +
                         vr[nb][2] * vr[nb][2] + 1e-8f);
        ts_sh[nb][t] = s_new[nb];
        ts_sh[nb][128 + t] = vn;
    }
    __syncthreads();

    const float* Wm1p = Wm1 + (size_t)layer * 256 * H;
    float hb = bm1[layer * H + t];
    float hacc[NB];
    #pragma unroll
    for (int nb = 0; nb < NB; nb++) hacc[nb] = hb;
    for (int h = 0; h < 256; h++) {
        float w = Wm1p[h * H + t];
        #pragma unroll
        for (int nb = 0; nb < NB; nb++) hacc[nb] += ts_sh[nb][h] * w;
    }
    #pragma unroll
    for (int nb = 0; nb < NB; nb++) {
        float z = hacc[nb];
        hid_sh[nb][t] = z / (1.f + expf(-z));
    }
    __syncthreads();

    const float* Wm2p = Wm2 + (size_t)layer * H * 384;
    float c0 = bm2[layer * 384 + t];
    float c1 = bm2[layer * 384 + 128 + t];
    float c2 = bm2[layer * 384 + 256 + t];
    float m0[NB], m1[NB], m2[NB];
    #pragma unroll
    for (int nb = 0; nb < NB; nb++) { m0[nb] = c0; m1[nb] = c1; m2[nb] = c2; }
    for (int h = 0; h < H; h++) {
        float w0 = Wm2p[h * 384 + t];
        float w1 = Wm2p[h * 384 + 128 + t];
        float w2 = Wm2p[h * 384 + 256 + t];
        #pragma unroll
        for (int nb = 0; nb < NB; nb++) {
            float hv = hid_sh[nb][h];
            m0[nb] += hv * w0; m1[nb] += hv * w1; m2[nb] += hv * w2;
        }
    }

    #pragma unroll
    for (int nb = 0; nb < NB; nb++) {
        int n = n0 + nb;
        if (n >= N_NODES) continue;
        float sum_lr = vr[nb][0] * vl[nb][0] + vr[nb][1] * vl[nb][1] +
                       vr[nb][2] * vl[nb][2];
        float s_out = (s_new[nb] + m0[nb] + m2[nb] * sum_lr) * eps;
        s[(size_t)n * H + t] = s_out;
        #pragma unroll
        for (int k = 0; k < 3; k++) {
            v[(size_t)n * 384 + k * H + t] =
                (v_sh[nb][k][t] + vl[nb][k] * m1[nb]) * eps;
        }
    }
}

extern "C" void kernel_launch(void* const* d_in, const int* in_sizes, int n_in,
                              void* d_out, int out_size, void* d_ws, size_t ws_size,
                              hipStream_t stream) {
    const int*   species   = (const int*)d_in[0];
    const int*   senders   = (const int*)d_in[1];
    const int*   receivers = (const int*)d_in[2];
    const float* dir_ij    = (const float*)d_in[3];
    const float* dists     = (const float*)d_in[4];
    const float* emb       = (const float*)d_in[5];
    const float* Wf        = (const float*)d_in[6];
    const float* bf        = (const float*)d_in[7];
    const float* W1        = (const float*)d_in[8];
    const float* b1        = (const float*)d_in[9];
    const float* W2        = (const float*)d_in[10];
    const float* b2        = (const float*)d_in[11];
    const float* Wvm       = (const float*)d_in[12];
    const float* Wm1       = (const float*)d_in[13];
    const float* bm1       = (const float*)d_in[14];
    const float* Wm2       = (const float*)d_in[15];
    const float* bm2       = (const float*)d_in[16];
    const float* eps_raw   = (const float*)d_in[17];

    float* s = (float*)d_out;                            // N*H
    float* v = (float*)d_out + (size_t)N_NODES * H;      // N*3*H

    float* x      = (float*)d_ws;                        // N*384
    float* ds_acc = x + (size_t)N_NODES * 384;           // N*128
    float* dv_acc = ds_acc + (size_t)N_NODES * H;        // N*384
    int*   cursor   = (int*)(dv_acc + (size_t)N_NODES * 384);  // N
    int*   offsets  = cursor + N_NODES;                        // N+1 (+pad)
    int*   edge_ids = offsets + N_NODES + 8;                   // E
    float* rbf      = (float*)(edge_ids + N_EDGES);            // E*20

    // CSR build (layer-independent) + rbf precompute
    hipMemsetAsync(cursor, 0, N_NODES * sizeof(int), stream);
    count_kernel<<<(N_EDGES + 255) / 256, 256, 0, stream>>>(senders, cursor);
    scan_kernel<<<1, 1024, 0, stream>>>(cursor, offsets);
    fill_kernel<<<(N_EDGES + 255) / 256, 256, 0, stream>>>(senders, cursor, edge_ids);
    rbfenv_kernel<<<(N_EDGES * 20 + 255) / 256, 256, 0, stream>>>(dists, rbf);

    // init: v = 0, s = emb[species]
    hipMemsetAsync(v, 0, (size_t)N_NODES * 384 * sizeof(float), stream);
    init_s_kernel<<<(N_NODES * H + 255) / 256, 256, 0, stream>>>(species, emb, s);

    for (int layer = 0; layer < 2; layer++) {
        node_mlp_kernel<<<(N_NODES + NBM - 1) / NBM, 128, 0, stream>>>(
            s, W1, b1, W2, b2, x, layer);
        aggregate_kernel<<<N_NODES, 128, 0, stream>>>(
            receivers, offsets, edge_ids, dir_ij, dists, rbf, Wf, bf, x, v,
            ds_acc, dv_acc, layer);
        node_update_kernel<<<(N_NODES + NB - 1) / NB, 128, 0, stream>>>(
            s, v, ds_acc, dv_acc, Wvm, Wm1, bm1, Wm2, bm2, eps_raw, layer);
    }
}

// Round 9
// 1164.918 us; speedup vs baseline: 1.8530x; 1.0883x over previous
//
#include <hip/hip_runtime.h>
#include <hip/hip_bf16.h>

#define N_NODES 25000
#define N_EDGES 400000
#define H 128
#define NB 8           // nodes per block in node_update
#define NBM 16         // nodes per block in node_mlp

__global__ void init_s_kernel(const int* __restrict__ species,
                              const float* __restrict__ emb,
                              float* __restrict__ s) {
    int idx = blockIdx.x * blockDim.x + threadIdx.x;
    if (idx < N_NODES * H) {
        int n = idx >> 7;
        int h = idx & 127;
        s[idx] = emb[species[n] * H + h];
    }
}

// ---------- CSR build over senders ----------
__global__ void count_kernel(const int* __restrict__ senders, int* __restrict__ cnt) {
    int e = blockIdx.x * blockDim.x + threadIdx.x;
    if (e < N_EDGES) atomicAdd(&cnt[senders[e]], 1);
}

__global__ __launch_bounds__(1024) void scan_kernel(int* __restrict__ cnt,
                                                    int* __restrict__ offsets) {
    __shared__ int sh[1024];
    const int t = threadIdx.x;
    const int CH = 25;                    // 1024*25 >= 25000
    int base = t * CH;
    int lc[CH];
    int lsum = 0;
    #pragma unroll
    for (int i = 0; i < CH; i++) {
        int idx = base + i;
        int c = (idx < N_NODES) ? cnt[idx] : 0;
        lc[i] = c; lsum += c;
    }
    sh[t] = lsum;
    __syncthreads();
    for (int ofs = 1; ofs < 1024; ofs <<= 1) {
        int v = (t >= ofs) ? sh[t - ofs] : 0;
        __syncthreads();
        sh[t] += v;
        __syncthreads();
    }
    int run = (t > 0) ? sh[t - 1] : 0;
    #pragma unroll
    for (int i = 0; i < CH; i++) {
        int idx = base + i;
        if (idx < N_NODES) {
            offsets[idx] = run;
            cnt[idx] = run;               // cnt becomes the fill cursor
            run += lc[i];
        }
    }
    if (t == 1023) offsets[N_NODES] = sh[1023];
}

__global__ void fill_kernel(const int* __restrict__ senders,
                            int* __restrict__ cursor, int* __restrict__ edge_ids) {
    int e = blockIdx.x * blockDim.x + threadIdx.x;
    if (e < N_EDGES) {
        int pos = atomicAdd(&cursor[senders[e]], 1);
        edge_ids[pos] = e;
    }
}

// rbf[e][n] = sqrt(2)*sin((n+1)*pi*d)/d
__global__ void rbfenv_kernel(const float* __restrict__ dists,
                              float* __restrict__ rbf) {
    int idx = blockIdx.x * blockDim.x + threadIdx.x;
    if (idx < N_EDGES * 20) {
        int e = idx / 20;
        int n = idx - e * 20;
        float d = dists[e];
        const float PI = 3.14159265358979323846f;
        rbf[idx] = 1.4142135623730951f * sinf((float)(n + 1) * PI * d) / d;
    }
}

// x = silu(s @ W1[i] + b1[i]) @ W2[i] + b2[i]   (per node: 128 -> 128 -> 384)
__global__ __launch_bounds__(128, 4) void node_mlp_kernel(
    const float* __restrict__ s,
    const float* __restrict__ W1, const float* __restrict__ b1,
    const float* __restrict__ W2, const float* __restrict__ b2,
    float* __restrict__ x, int layer)
{
    __shared__ float s_sh[NBM][H];
    __shared__ float hid_sh[NBM][H];
    const int t = threadIdx.x;
    const int n0 = blockIdx.x * NBM;

    #pragma unroll
    for (int nb = 0; nb < NBM; nb++) {
        int n = n0 + nb;
        s_sh[nb][t] = (n < N_NODES) ? s[(size_t)n * H + t] : 0.f;
    }
    __syncthreads();

    const float* W1p = W1 + (size_t)layer * H * H;
    float b1v = b1[layer * H + t];
    float acc[NBM];
    #pragma unroll
    for (int nb = 0; nb < NBM; nb++) acc[nb] = b1v;
    for (int h = 0; h < H; h += 4) {
        float w[4];
        #pragma unroll
        for (int hh = 0; hh < 4; hh++) w[hh] = W1p[(h + hh) * H + t];
        #pragma unroll
        for (int nb = 0; nb < NBM; nb++) {
            float4 sv = *(const float4*)&s_sh[nb][h];
            acc[nb] = fmaf(sv.x, w[0], fmaf(sv.y, w[1],
                      fmaf(sv.z, w[2], fmaf(sv.w, w[3], acc[nb]))));
        }
    }
    #pragma unroll
    for (int nb = 0; nb < NBM; nb++) {
        float z = acc[nb];
        hid_sh[nb][t] = z / (1.f + expf(-z));   // silu
    }
    __syncthreads();

    const float* W2p = W2 + (size_t)layer * H * 384;
    float c0 = b2[layer * 384 + t];
    float c1 = b2[layer * 384 + 128 + t];
    float c2 = b2[layer * 384 + 256 + t];
    float a0[NBM], a1[NBM], a2[NBM];
    #pragma unroll
    for (int nb = 0; nb < NBM; nb++) { a0[nb] = c0; a1[nb] = c1; a2[nb] = c2; }
    for (int h = 0; h < H; h++) {
        float w0 = W2p[h * 384 + t];
        float w1 = W2p[h * 384 + 128 + t];
        float w2 = W2p[h * 384 + 256 + t];
        #pragma unroll
        for (int nb = 0; nb < NBM; nb++) {
            float hv = hid_sh[nb][h];
            a0[nb] += hv * w0; a1[nb] += hv * w1; a2[nb] += hv * w2;
        }
    }
    #pragma unroll
    for (int nb = 0; nb < NBM; nb++) {
        int n = n0 + nb;
        if (n < N_NODES) {
            x[(size_t)n * 384 + t]       = a0[nb];
            x[(size_t)n * 384 + 128 + t] = a1[nb];
            x[(size_t)n * 384 + 256 + t] = a2[nb];
        }
    }
}

// Gather-based edge aggregation: one block (128 threads) per sender node.
__global__ __launch_bounds__(128, 4) void aggregate_kernel(
    const int* __restrict__ receivers,
    const int* __restrict__ offsets, const int* __restrict__ edge_ids,
    const float* __restrict__ dir_ij, const float* __restrict__ dists,
    const float* __restrict__ rbf,
    const float* __restrict__ Wf, const float* __restrict__ bfb,
    const float* __restrict__ x, const float* __restrict__ v,
    float* __restrict__ ds_acc, float* __restrict__ dv_acc, int layer)
{
    const int t = threadIdx.x;          // feature 0..127
    const int node = blockIdx.x;

    const float* Wfp = Wf + layer * 384;       // row stride 768 (L*3*H)
    float wf0[20], wf1[20], wf2[20];
    #pragma unroll
    for (int n = 0; n < 20; n++) {
        wf0[n] = Wfp[n * 768 + t];
        wf1[n] = Wfp[n * 768 + 128 + t];
        wf2[n] = Wfp[n * 768 + 256 + t];
    }
    float bf0 = bfb[layer * 384 + t];
    float bf1 = bfb[layer * 384 + 128 + t];
    float bf2 = bfb[layer * 384 + 256 + t];

    float accs = 0.f, av0 = 0.f, av1 = 0.f, av2 = 0.f;
    const int beg = offsets[node], end = offsets[node + 1];

    for (int j = beg; j < end; j++) {
        int eid = edge_ids[j];
        int rcv = receivers[eid];
        float d  = dists[eid];
        float d0 = dir_ij[eid * 3 + 0];
        float d1 = dir_ij[eid * 3 + 1];
        float d2 = dir_ij[eid * 3 + 2];

        float u = d;
        float u2 = u * u, u4 = u2 * u2, u6 = u4 * u2, u7 = u6 * u, u8 = u4 * u4;
        float env = (u < 1.f) ? (1.f - 28.f * u6 + 48.f * u7 - 21.f * u8) : 0.f;

        const float4* rp = (const float4*)(rbf + (size_t)eid * 20);
        float4 q0 = rp[0], q1 = rp[1], q2 = rp[2], q3 = rp[3], q4 = rp[4];
        float r[20] = { q0.x, q0.y, q0.z, q0.w, q1.x, q1.y, q1.z, q1.w,
                        q2.x, q2.y, q2.z, q2.w, q3.x, q3.y, q3.z, q3.w,
                        q4.x, q4.y, q4.z, q4.w };

        float w0 = bf0, w1 = bf1, w2 = bf2;
        #pragma unroll
        for (int n = 0; n < 20; n++) {
            w0 = fmaf(r[n], wf0[n], w0);
            w1 = fmaf(r[n], wf1[n], w1);
            w2 = fmaf(r[n], wf2[n], w2);
        }
        const float* xr = x + (size_t)rcv * 384;
        const float* vr = v + (size_t)rcv * 384;
        float phi0 = w0 * env * xr[t];
        float phi1 = w1 * env * xr[128 + t];
        float phi2 = w2 * env * xr[256 + t];

        accs += phi0;
        av0 = fmaf(phi1, d0, fmaf(phi2, vr[t],       av0));
        av1 = fmaf(phi1, d1, fmaf(phi2, vr[128 + t], av1));
        av2 = fmaf(phi1, d2, fmaf(phi2, vr[256 + t], av2));
    }

    ds_acc[(size_t)node * H + t] = accs;
    dv_acc[(size_t)node * 384 + t]       = av0;
    dv_acc[(size_t)node * 384 + 128 + t] = av1;
    dv_acc[(size_t)node * 384 + 256 + t] = av2;
}

// Apply segment sums, then gated vector/scalar mixing block.
// LDS: v_sh (12KB) + ts_sh (8KB); silu(hid) aliases ts_sh after Wm1 loop.
// All broadcast LDS reads vectorized to float4 (ds_read_b128).
__global__ __launch_bounds__(128, 4) void node_update_kernel(
    float* __restrict__ s, float* __restrict__ v,
    const float* __restrict__ ds_acc, const float* __restrict__ dv_acc,
    const float* __restrict__ Wvm,
    const float* __restrict__ Wm1, const float* __restrict__ bm1,
    const float* __restrict__ Wm2, const float* __restrict__ bm2,
    const float* __restrict__ eps_raw_p, int layer)
{
    __shared__ float v_sh[NB][3][H];
    __shared__ float ts_sh[NB][2 * H];   // reused as hid after Wm1 loop
    const int t = threadIdx.x;
    const int n0 = blockIdx.x * NB;
    float er = eps_raw_p[0];
    float eps = rsqrtf(1.f + er * er);

    float s_new[NB];
    #pragma unroll
    for (int nb = 0; nb < NB; nb++) {
        int n = n0 + nb;
        if (n < N_NODES) {
            float sv = (s[(size_t)n * H + t] + ds_acc[(size_t)n * H + t]) * eps;
            s_new[nb] = sv;
            #pragma unroll
            for (int k = 0; k < 3; k++) {
                float vv = (v[(size_t)n * 384 + k * H + t] +
                            dv_acc[(size_t)n * 384 + k * H + t]) * eps;
                v_sh[nb][k][t] = vv;
            }
        } else {
            s_new[nb] = 0.f;
            #pragma unroll
            for (int k = 0; k < 3; k++) v_sh[nb][k][t] = 0.f;
        }
    }
    __syncthreads();

    // vw = v @ Wvm[i]; thread t holds columns t (v_l) and 128+t (v_r)
    const float* Wvp = Wvm + (size_t)layer * H * 256;
    float vl[NB][3], vr[NB][3];
    #pragma unroll
    for (int nb = 0; nb < NB; nb++)
        #pragma unroll
        for (int k = 0; k < 3; k++) { vl[nb][k] = 0.f; vr[nb][k] = 0.f; }
    for (int h = 0; h < H; h += 4) {
        float wl[4], wr[4];
        #pragma unroll
        for (int hh = 0; hh < 4; hh++) {
            wl[hh] = Wvp[(h + hh) * 256 + t];
            wr[hh] = Wvp[(h + hh) * 256 + 128 + t];
        }
        #pragma unroll
        for (int nb = 0; nb < NB; nb++) {
            #pragma unroll
            for (int k = 0; k < 3; k++) {
                float4 vv = *(const float4*)&v_sh[nb][k][h];
                vl[nb][k] = fmaf(vv.x, wl[0], fmaf(vv.y, wl[1],
                            fmaf(vv.z, wl[2], fmaf(vv.w, wl[3], vl[nb][k]))));
                vr[nb][k] = fmaf(vv.x, wr[0], fmaf(vv.y, wr[1],
                            fmaf(vv.z, wr[2], fmaf(vv.w, wr[3], vr[nb][k]))));
            }
        }
    }

    #pragma unroll
    for (int nb = 0; nb < NB; nb++) {
        float vn = sqrtf(vr[nb][0] * vr[nb][0] + vr[nb][1] * vr[nb][1] +
                         vr[nb][2] * vr[nb][2] + 1e-8f);
        ts_sh[nb][t] = s_new[nb];
        ts_sh[nb][128 + t] = vn;
    }
    __syncthreads();

    const float* Wm1p = Wm1 + (size_t)layer * 256 * H;
    float hb = bm1[layer * H + t];
    float hacc[NB];
    #pragma unroll
    for (int nb = 0; nb < NB; nb++) hacc[nb] = hb;
    for (int h = 0; h < 2 * H; h += 4) {
        float w[4];
        #pragma unroll
        for (int hh = 0; hh < 4; hh++) w[hh] = Wm1p[(h + hh) * H + t];
        #pragma unroll
        for (int nb = 0; nb < NB; nb++) {
            float4 tv = *(const float4*)&ts_sh[nb][h];
            hacc[nb] = fmaf(tv.x, w[0], fmaf(tv.y, w[1],
                       fmaf(tv.z, w[2], fmaf(tv.w, w[3], hacc[nb]))));
        }
    }
    __syncthreads();   // all ts reads done before aliasing

    #pragma unroll
    for (int nb = 0; nb < NB; nb++) {
        float z = hacc[nb];
        ts_sh[nb][t] = z / (1.f + expf(-z));   // hid aliases ts
    }
    __syncthreads();

    const float* Wm2p = Wm2 + (size_t)layer * H * 384;
    float c0 = bm2[layer * 384 + t];
    float c1 = bm2[layer * 384 + 128 + t];
    float c2 = bm2[layer * 384 + 256 + t];
    float m0[NB], m1[NB], m2[NB];
    #pragma unroll
    for (int nb = 0; nb < NB; nb++) { m0[nb] = c0; m1[nb] = c1; m2[nb] = c2; }
    for (int h = 0; h < H; h += 4) {
        float w0[4], w1[4], w2[4];
        #pragma unroll
        for (int hh = 0; hh < 4; hh++) {
            w0[hh] = Wm2p[(h + hh) * 384 + t];
            w1[hh] = Wm2p[(h + hh) * 384 + 128 + t];
            w2[hh] = Wm2p[(h + hh) * 384 + 256 + t];
        }
        #pragma unroll
        for (int nb = 0; nb < NB; nb++) {
            float4 hv = *(const float4*)&ts_sh[nb][h];
            m0[nb] = fmaf(hv.x, w0[0], fmaf(hv.y, w0[1],
                     fmaf(hv.z, w0[2], fmaf(hv.w, w0[3], m0[nb]))));
            m1[nb] = fmaf(hv.x, w1[0], fmaf(hv.y, w1[1],
                     fmaf(hv.z, w1[2], fmaf(hv.w, w1[3], m1[nb]))));
            m2[nb] = fmaf(hv.x, w2[0], fmaf(hv.y, w2[1],
                     fmaf(hv.z, w2[2], fmaf(hv.w, w2[3], m2[nb]))));
        }
    }

    #pragma unroll
    for (int nb = 0; nb < NB; nb++) {
        int n = n0 + nb;
        if (n >= N_NODES) continue;
        float sum_lr = vr[nb][0] * vl[nb][0] + vr[nb][1] * vl[nb][1] +
                       vr[nb][2] * vl[nb][2];
        float s_out = (s_new[nb] + m0[nb] + m2[nb] * sum_lr) * eps;
        s[(size_t)n * H + t] = s_out;
        #pragma unroll
        for (int k = 0; k < 3; k++) {
            v[(size_t)n * 384 + k * H + t] =
                (v_sh[nb][k][t] + vl[nb][k] * m1[nb]) * eps;
        }
    }
}

extern "C" void kernel_launch(void* const* d_in, const int* in_sizes, int n_in,
                              void* d_out, int out_size, void* d_ws, size_t ws_size,
                              hipStream_t stream) {
    const int*   species   = (const int*)d_in[0];
    const int*   senders   = (const int*)d_in[1];
    const int*   receivers = (const int*)d_in[2];
    const float* dir_ij    = (const float*)d_in[3];
    const float* dists     = (const float*)d_in[4];
    const float* emb       = (const float*)d_in[5];
    const float* Wf        = (const float*)d_in[6];
    const float* bf        = (const float*)d_in[7];
    const float* W1        = (const float*)d_in[8];
    const float* b1        = (const float*)d_in[9];
    const float* W2        = (const float*)d_in[10];
    const float* b2        = (const float*)d_in[11];
    const float* Wvm       = (const float*)d_in[12];
    const float* Wm1       = (const float*)d_in[13];
    const float* bm1       = (const float*)d_in[14];
    const float* Wm2       = (const float*)d_in[15];
    const float* bm2       = (const float*)d_in[16];
    const float* eps_raw   = (const float*)d_in[17];

    float* s = (float*)d_out;                            // N*H
    float* v = (float*)d_out + (size_t)N_NODES * H;      // N*3*H

    float* x      = (float*)d_ws;                        // N*384
    float* ds_acc = x + (size_t)N_NODES * 384;           // N*128
    float* dv_acc = ds_acc + (size_t)N_NODES * H;        // N*384
    int*   cursor   = (int*)(dv_acc + (size_t)N_NODES * 384);  // N
    int*   offsets  = cursor + N_NODES;                        // N+1 (+pad)
    int*   edge_ids = offsets + N_NODES + 8;                   // E
    float* rbf      = (float*)(edge_ids + N_EDGES);            // E*20

    // CSR build (layer-independent) + rbf precompute
    hipMemsetAsync(cursor, 0, N_NODES * sizeof(int), stream);
    count_kernel<<<(N_EDGES + 255) / 256, 256, 0, stream>>>(senders, cursor);
    scan_kernel<<<1, 1024, 0, stream>>>(cursor, offsets);
    fill_kernel<<<(N_EDGES + 255) / 256, 256, 0, stream>>>(senders, cursor, edge_ids);
    rbfenv_kernel<<<(N_EDGES * 20 + 255) / 256, 256, 0, stream>>>(dists, rbf);

    // init: v = 0, s = emb[species]
    hipMemsetAsync(v, 0, (size_t)N_NODES * 384 * sizeof(float), stream);
    init_s_kernel<<<(N_NODES * H + 255) / 256, 256, 0, stream>>>(species, emb, s);

    for (int layer = 0; layer < 2; layer++) {
        node_mlp_kernel<<<(N_NODES + NBM - 1) / NBM, 128, 0, stream>>>(
            s, W1, b1, W2, b2, x, layer);
        aggregate_kernel<<<N_NODES, 128, 0, stream>>>(
            receivers, offsets, edge_ids, dir_ij, dists, rbf, Wf, bf, x, v,
            ds_acc, dv_acc, layer);
        node_update_kernel<<<(N_NODES + NB - 1) / NB, 128, 0, stream>>>(
            s, v, ds_acc, dv_acc, Wvm, Wm1, bm1, Wm2, bm2, eps_raw, layer);
    }
}